// Round 12
// baseline (78.858 us; speedup 1.0000x reference)
//
#include <hip/hip_runtime.h>
#include <math.h>

#define EMBED 1024
#define SEQ   2048
#define HEAD  64
#define NROW  8192   /* BATCH*SEQ */

// ---------------------------------------------------------------------------
// Round 12: pipeline the two hot kernels (structure unchanged from round 11).
//  qkv_fused: W-fragment REGISTER double-buffer (prefetch chunk c+1 during
//             chunk c's MFMAs; manual 2x unroll keeps indices static).
//  attn_mfma: K/V LDS double-buffer + reg prefetch, 1 barrier/tile;
//             chunk 8->4 key-tiles => grid 1152 (4.5 blocks/CU).
//  attn_combine: decode updated (np = qb/8+1 partials, up to 8).
// ws: Wt 0.66 | Qh Ql Kh Kl Vr Vt 6x1MB | PO 5.01MB = 11.96MB total.
// ---------------------------------------------------------------------------

typedef float f32x4  __attribute__((ext_vector_type(4)));
typedef short bf16x8 __attribute__((ext_vector_type(8)));

__device__ __forceinline__ ushort f2bf(float v) {
    union { float f; unsigned u; } t; t.f = v;
    unsigned r = t.u + 0x7FFFu + ((t.u >> 16) & 1u);   // RNE
    return (ushort)(r >> 16);
}
__device__ __forceinline__ float bf2f(ushort h) {
    union { float f; unsigned u; } t; t.u = ((unsigned)h) << 16;
    return t.f;
}
__device__ __forceinline__ uint4 pack8(const ushort* o) {
    uint4 u;
    u.x = (unsigned)o[0] | ((unsigned)o[1] << 16);
    u.y = (unsigned)o[2] | ((unsigned)o[3] << 16);
    u.z = (unsigned)o[4] | ((unsigned)o[5] << 16);
    u.w = (unsigned)o[6] | ((unsigned)o[7] << 16);
    return u;
}

// ---------------------------------------------------------------------------
__global__ __launch_bounds__(256)
void prep_w(const float* __restrict__ Wq, const float* __restrict__ Wk,
            const float* __restrict__ Wv, ushort* __restrict__ Wt)
{
    const int id = blockIdx.x * 256 + threadIdx.x;   // 0..40959
    const int g  = id / 2560;
    const int r1 = id - g * 2560;
    const int s  = r1 >> 6, l = r1 & 63;
    int f, hl, ks;
    if (s < 32) { f = s >> 2; hl = (s >> 1) & 1; ks = s & 1; }
    else        { int t = s - 32; f = 8 + (t >> 1); hl = 0; ks = t & 1; }
    const float* W = (f < 4) ? Wq : (f < 8) ? Wk : Wv;
    const int col = (f & 3) * 16 + (l & 15);
    const int k   = g * 64 + ks * 32 + (l >> 4) * 8;
    float4 v0 = *(const float4*)&W[(size_t)col * EMBED + k];
    float4 v1 = *(const float4*)&W[(size_t)col * EMBED + k + 4];
    const float vv[8] = {v0.x, v0.y, v0.z, v0.w, v1.x, v1.y, v1.z, v1.w};
    ushort o[8];
#pragma unroll
    for (int i = 0; i < 8; ++i) {
        const ushort h = f2bf(vv[i]);
        o[i] = hl ? f2bf(vv[i] - bf2f(h)) : h;
    }
    *(uint4*)&Wt[((size_t)g * 40 + s) * 512 + l * 8] = pack8(o);
}

// ---------------------------------------------------------------------------
// qkv_fused: 16 rows x 192 cols x K=1024 per block, grid 512 (2 blocks/CU).
// W frags global->reg, double-buffered; x staged in dbuf LDS.
// ---------------------------------------------------------------------------
__global__ __launch_bounds__(256)
void qkv_fused(const float* __restrict__ x, const ushort* __restrict__ Wt,
               ushort* __restrict__ Qh, ushort* __restrict__ Ql,
               ushort* __restrict__ Kh, ushort* __restrict__ Kl,
               ushort* __restrict__ Vr)
{
    __shared__ ushort SA[2][4 * 512];     // x tile: [hl*2+ks][oc*128+row*8]
    __shared__ float  T[3 * 16 * 68];     // epilogue scratch

    const int tid  = threadIdx.x;
    const int w    = tid >> 6;
    const int lane = tid & 63;
    const int row0 = blockIdx.x * 16;

    const int  srow = tid >> 3, so8 = tid & 7;
    const int  sks  = so8 >> 2, soc = so8 & 3;
    const bool sact = (tid < 128);

    f32x4 acc[3];
#pragma unroll
    for (int fi = 0; fi < 3; ++fi) acc[fi] = (f32x4){0.f, 0.f, 0.f, 0.f};

    bf16x8 wA[10], wB[10];

    // ---- prologue: chunk-0 x commit + chunk-0 W frags into wA ----
    {
        const float* xp = &x[(size_t)(row0 + srow) * EMBED + so8 * 8];
        float4 xa, xb;
        if (sact) { xa = *(const float4*)xp; xb = *(const float4*)(xp + 4); }
        const ushort* Wg = &Wt[0 + lane * 8];
#pragma unroll
        for (int ks = 0; ks < 2; ++ks) {
            wA[ks * 5 + 0] = *(const bf16x8*)&Wg[(size_t)(w * 4 + ks) * 512];
            wA[ks * 5 + 1] = *(const bf16x8*)&Wg[(size_t)(w * 4 + 2 + ks) * 512];
            wA[ks * 5 + 2] = *(const bf16x8*)&Wg[(size_t)((w + 4) * 4 + ks) * 512];
            wA[ks * 5 + 3] = *(const bf16x8*)&Wg[(size_t)((w + 4) * 4 + 2 + ks) * 512];
            wA[ks * 5 + 4] = *(const bf16x8*)&Wg[(size_t)(32 + w * 2 + ks) * 512];
        }
        if (sact) {
            const float vv[8] = {xa.x, xa.y, xa.z, xa.w, xb.x, xb.y, xb.z, xb.w};
            ushort hs[8], ls[8];
#pragma unroll
            for (int i = 0; i < 8; ++i) { hs[i] = f2bf(vv[i]); ls[i] = f2bf(vv[i] - bf2f(hs[i])); }
            const int base = soc * 128 + srow * 8;
            *(uint4*)&SA[0][sks * 512 + base]       = pack8(hs);
            *(uint4*)&SA[0][(2 + sks) * 512 + base] = pack8(ls);
        }
    }
    __syncthreads();

    auto chunk = [&](int c, bf16x8* wc, bf16x8* wn) {
        const int cur = c & 1;
        const bool pre = (c + 1 < 16);
        float4 xa, xb;
        if (pre && sact) {
            const float* xp = &x[(size_t)(row0 + srow) * EMBED + (c + 1) * 64 + so8 * 8];
            xa = *(const float4*)xp; xb = *(const float4*)(xp + 4);
        }
        if (pre) {
            const ushort* Wg = &Wt[((size_t)(c + 1) * 40) * 512 + lane * 8];
#pragma unroll
            for (int ks = 0; ks < 2; ++ks) {
                wn[ks * 5 + 0] = *(const bf16x8*)&Wg[(size_t)(w * 4 + ks) * 512];
                wn[ks * 5 + 1] = *(const bf16x8*)&Wg[(size_t)(w * 4 + 2 + ks) * 512];
                wn[ks * 5 + 2] = *(const bf16x8*)&Wg[(size_t)((w + 4) * 4 + ks) * 512];
                wn[ks * 5 + 3] = *(const bf16x8*)&Wg[(size_t)((w + 4) * 4 + 2 + ks) * 512];
                wn[ks * 5 + 4] = *(const bf16x8*)&Wg[(size_t)(32 + w * 2 + ks) * 512];
            }
        }
#pragma unroll
        for (int ks = 0; ks < 2; ++ks) {
            bf16x8 ah = *(const bf16x8*)&SA[cur][ks * 512 + lane * 8];
            bf16x8 al = *(const bf16x8*)&SA[cur][(2 + ks) * 512 + lane * 8];
            acc[0] = __builtin_amdgcn_mfma_f32_16x16x32_bf16(ah, wc[ks * 5 + 0], acc[0], 0, 0, 0);
            acc[0] = __builtin_amdgcn_mfma_f32_16x16x32_bf16(ah, wc[ks * 5 + 1], acc[0], 0, 0, 0);
            acc[0] = __builtin_amdgcn_mfma_f32_16x16x32_bf16(al, wc[ks * 5 + 0], acc[0], 0, 0, 0);
            acc[1] = __builtin_amdgcn_mfma_f32_16x16x32_bf16(ah, wc[ks * 5 + 2], acc[1], 0, 0, 0);
            acc[1] = __builtin_amdgcn_mfma_f32_16x16x32_bf16(ah, wc[ks * 5 + 3], acc[1], 0, 0, 0);
            acc[1] = __builtin_amdgcn_mfma_f32_16x16x32_bf16(al, wc[ks * 5 + 2], acc[1], 0, 0, 0);
            acc[2] = __builtin_amdgcn_mfma_f32_16x16x32_bf16(ah, wc[ks * 5 + 4], acc[2], 0, 0, 0);
        }
        if (pre && sact) {
            const float vv[8] = {xa.x, xa.y, xa.z, xa.w, xb.x, xb.y, xb.z, xb.w};
            ushort hs[8], ls[8];
#pragma unroll
            for (int i = 0; i < 8; ++i) { hs[i] = f2bf(vv[i]); ls[i] = f2bf(vv[i] - bf2f(hs[i])); }
            const int base = soc * 128 + srow * 8;
            *(uint4*)&SA[cur ^ 1][sks * 512 + base]       = pack8(hs);
            *(uint4*)&SA[cur ^ 1][(2 + sks) * 512 + base] = pack8(ls);
        }
        __syncthreads();
    };

    for (int cc = 0; cc < 16; cc += 2) {
        chunk(cc,     wA, wB);
        chunk(cc + 1, wB, wA);
    }

    // ---- epilogue: acc -> T -> final bf16 outputs ----
#pragma unroll
    for (int fi = 0; fi < 3; ++fi)
#pragma unroll
        for (int r = 0; r < 4; ++r)
            T[(fi * 16 + 4 * (lane >> 4) + r) * 68 + w * 16 + (lane & 15)] = acc[fi][r];
    __syncthreads();

    const int orow = tid >> 4, oc4 = tid & 15;
    const size_t obase = (size_t)(row0 + orow) * HEAD + oc4 * 4;
    {   // Q: scale 32, split
        float4 v = *(const float4*)&T[(orow) * 68 + oc4 * 4];
        const float vv[4] = {32.f * v.x, 32.f * v.y, 32.f * v.z, 32.f * v.w};
        ushort h[4], l[4];
#pragma unroll
        for (int i = 0; i < 4; ++i) { h[i] = f2bf(vv[i]); l[i] = f2bf(vv[i] - bf2f(h[i])); }
        *(ushort4*)&Qh[obase] = make_ushort4(h[0], h[1], h[2], h[3]);
        *(ushort4*)&Ql[obase] = make_ushort4(l[0], l[1], l[2], l[3]);
    }
    {   // K: split
        float4 v = *(const float4*)&T[(16 + orow) * 68 + oc4 * 4];
        const float vv[4] = {v.x, v.y, v.z, v.w};
        ushort h[4], l[4];
#pragma unroll
        for (int i = 0; i < 4; ++i) { h[i] = f2bf(vv[i]); l[i] = f2bf(vv[i] - bf2f(h[i])); }
        *(ushort4*)&Kh[obase] = make_ushort4(h[0], h[1], h[2], h[3]);
        *(ushort4*)&Kl[obase] = make_ushort4(l[0], l[1], l[2], l[3]);
    }
    {   // V: hi only, row-major
        float4 v = *(const float4*)&T[(32 + orow) * 68 + oc4 * 4];
        *(ushort4*)&Vr[obase] =
            make_ushort4(f2bf(v.x), f2bf(v.y), f2bf(v.z), f2bf(v.w));
    }
}

// ---------------------------------------------------------------------------
__global__ __launch_bounds__(256)
void v_transpose(const ushort* __restrict__ Vr, ushort* __restrict__ Vt)
{
    __shared__ ushort T2[64][264];
    const int s  = blockIdx.x;            // 0..31
    const int b  = s >> 3;
    const int k0 = (s & 7) * 256;
    const int tid = threadIdx.x;
#pragma unroll
    for (int i = 0; i < 8; ++i) {
        const int u = tid + 256 * i;      // 0..2047
        const int row = u >> 3, c8 = u & 7;
        uint4 v = *(const uint4*)&Vr[((size_t)(b * SEQ + k0 + row)) * HEAD + c8 * 8];
        const ushort* e = (const ushort*)&v;
#pragma unroll
        for (int j = 0; j < 8; ++j) T2[c8 * 8 + j][row] = e[j];
    }
    __syncthreads();
#pragma unroll
    for (int i = 0; i < 8; ++i) {
        const int u = tid + 256 * i;      // 0..2047
        const int d = u >> 5, c8 = u & 31;
        uint4 val = *(const uint4*)&T2[d][c8 * 8];
        *(uint4*)&Vt[((size_t)(b * 64 + d)) * SEQ + k0 + c8 * 8] = val;
    }
}

// ---------------------------------------------------------------------------
// attn_mfma: item = (b, qb32, chunk of <=4 key-tiles), grid 1152.
// 2 waves x 16q; dbuf K/V LDS + reg prefetch, 1 barrier per tile.
// ---------------------------------------------------------------------------
__global__ __launch_bounds__(128)
void attn_mfma(const ushort* __restrict__ Qh, const ushort* __restrict__ Ql,
               const ushort* __restrict__ Kh, const ushort* __restrict__ Kl,
               const ushort* __restrict__ Vt, char* __restrict__ PO)
{
    const int id = blockIdx.x;            // 0..1151
    const int b  = id / 288;
    int f = id - 288 * b;
    int g2 = 0;                           // qb group (qb>>3)
    {
        int base = 0;
        while (f >= base + 8 * (g2 + 1)) { base += 8 * (g2 + 1); ++g2; }
        f -= base;
    }
    const int qb  = 8 * g2 + f / (g2 + 1);
    const int kc  = f - (g2 + 1) * (f / (g2 + 1));
    const int q0  = qb * 32;
    const int ktd = qb >> 1;              // diagonal tile
    const int nt  = ktd + 1;
    const int t0  = kc * 4;
    const int t1  = (t0 + 4 < nt) ? t0 + 4 : nt;

    const int tid = threadIdx.x;
    const int w   = tid >> 6;
    const int lane = tid & 63;
    const int g = lane >> 4, c = lane & 15;
    const int swz = (c & 7) << 3;

    __shared__ ushort KH[2][64 * 64];
    __shared__ ushort KL[2][64 * 64];
    __shared__ ushort VT[2][64 * 64];
    __shared__ ushort PS[2][16 * 64];

    // staging identities
    const int srow = tid >> 3, sc8 = tid & 7;
    const int sdst = srow * 64 + ((sc8 ^ (srow & 7)) * 8);

    // ---- Q frags ----
    const int qrow = q0 + 16 * w + c;
    bf16x8 qh[2], ql[2];
#pragma unroll
    for (int ks = 0; ks < 2; ++ks) {
        const size_t qi = ((size_t)(b * SEQ + qrow)) * HEAD + 32 * ks + 8 * g;
        qh[ks] = *(const bf16x8*)&Qh[qi];
        ql[ks] = *(const bf16x8*)&Ql[qi];
    }

    f32x4 o[4];
#pragma unroll
    for (int db = 0; db < 4; ++db) o[db] = (f32x4){0.f, 0.f, 0.f, 0.f};
    float m = -1e30f, lsum = 0.f;

    uint4 kreg[4], lreg[4], vreg[4];
    // ---- prologue: load + commit tile t0 ----
#pragma unroll
    for (int i = 0; i < 4; ++i) {
        const int row = srow + 16 * i;
        const size_t ksrc = ((size_t)(b * SEQ + t0 * 64 + row)) * HEAD + sc8 * 8;
        kreg[i] = *(const uint4*)&Kh[ksrc];
        lreg[i] = *(const uint4*)&Kl[ksrc];
        const size_t vsrc = ((size_t)(b * 64 + row)) * SEQ + t0 * 64 + sc8 * 8;
        vreg[i] = *(const uint4*)&Vt[vsrc];
    }
#pragma unroll
    for (int i = 0; i < 4; ++i) {
        const int dst = sdst + 16 * i * 64;
        *(uint4*)&KH[0][dst] = kreg[i];
        *(uint4*)&KL[0][dst] = lreg[i];
        *(uint4*)&VT[0][dst] = vreg[i];
    }
    __syncthreads();

    for (int kt = t0; kt < t1; ++kt) {
        const int cur = (kt - t0) & 1;
        const int kb0 = kt * 64;
        const bool pre = (kt + 1 < t1);
        // ---- issue next tile's loads ----
        if (pre) {
#pragma unroll
            for (int i = 0; i < 4; ++i) {
                const int row = srow + 16 * i;
                const size_t ksrc = ((size_t)(b * SEQ + kb0 + 64 + row)) * HEAD + sc8 * 8;
                kreg[i] = *(const uint4*)&Kh[ksrc];
                lreg[i] = *(const uint4*)&Kl[ksrc];
                const size_t vsrc = ((size_t)(b * 64 + row)) * SEQ + kb0 + 64 + sc8 * 8;
                vreg[i] = *(const uint4*)&Vt[vsrc];
            }
        }

        // ---- QK^T (swapped): 3-MFMA split-bf16 ----
        f32x4 s[4];
#pragma unroll
        for (int kb = 0; kb < 4; ++kb) s[kb] = (f32x4){0.f, 0.f, 0.f, 0.f};
#pragma unroll
        for (int ks = 0; ks < 2; ++ks) {
            const int co = (32 * ks + 8 * g) ^ swz;
#pragma unroll
            for (int kb = 0; kb < 4; ++kb) {
                const int row = 16 * kb + c;
                bf16x8 ah = *(const bf16x8*)&KH[cur][row * 64 + co];
                bf16x8 al = *(const bf16x8*)&KL[cur][row * 64 + co];
                s[kb] = __builtin_amdgcn_mfma_f32_16x16x32_bf16(ah, qh[ks], s[kb], 0, 0, 0);
                s[kb] = __builtin_amdgcn_mfma_f32_16x16x32_bf16(ah, ql[ks], s[kb], 0, 0, 0);
                s[kb] = __builtin_amdgcn_mfma_f32_16x16x32_bf16(al, qh[ks], s[kb], 0, 0, 0);
            }
        }

        if (kt == ktd) {
#pragma unroll
            for (int kb = 0; kb < 4; ++kb)
#pragma unroll
                for (int r = 0; r < 4; ++r)
                    if (kb0 + 16 * kb + 4 * g + r > qrow) s[kb][r] = -1e30f;
        }

        // ---- online softmax (lane-local) ----
        float tmax = -1e30f;
#pragma unroll
        for (int kb = 0; kb < 4; ++kb) {
            float a = fmaxf(fmaxf(s[kb][0], s[kb][1]), fmaxf(s[kb][2], s[kb][3]));
            tmax = fmaxf(tmax, a);
        }
        tmax = fmaxf(tmax, __shfl_xor(tmax, 16));
        tmax = fmaxf(tmax, __shfl_xor(tmax, 32));
        const float mnew = fmaxf(m, tmax);
        const float fac  = __expf(m - mnew);
        float p[4][4];
        float psum = 0.f;
#pragma unroll
        for (int kb = 0; kb < 4; ++kb)
#pragma unroll
            for (int r = 0; r < 4; ++r) {
                p[kb][r] = __expf(s[kb][r] - mnew);
                psum += p[kb][r];
            }
        psum += __shfl_xor(psum, 16);
        psum += __shfl_xor(psum, 32);
        lsum = lsum * fac + psum;
        m = mnew;

        float fb[4];
#pragma unroll
        for (int r = 0; r < 4; ++r) fb[r] = __shfl(fac, 4 * g + r);
#pragma unroll
        for (int db = 0; db < 4; ++db) {
            o[db][0] *= fb[0]; o[db][1] *= fb[1];
            o[db][2] *= fb[2]; o[db][3] *= fb[3];
        }

#pragma unroll
        for (int kb = 0; kb < 4; ++kb) {
            const int idx = c * 64 + (((16 * kb + 4 * g)) ^ swz);
            *(ushort4*)&PS[w][idx] = make_ushort4(
                f2bf(p[kb][0]), f2bf(p[kb][1]), f2bf(p[kb][2]), f2bf(p[kb][3]));
        }

#pragma unroll
        for (int k2 = 0; k2 < 2; ++k2) {
            const int co = (32 * k2 + 8 * g) ^ swz;
            bf16x8 pa = *(const bf16x8*)&PS[w][c * 64 + co];
#pragma unroll
            for (int db = 0; db < 4; ++db) {
                const int row = 16 * db + c;
                bf16x8 vb = *(const bf16x8*)&VT[cur][row * 64 + co];
                o[db] = __builtin_amdgcn_mfma_f32_16x16x32_bf16(pa, vb, o[db], 0, 0, 0);
            }
        }

        // ---- commit prefetched tile ----
        if (pre) {
#pragma unroll
            for (int i = 0; i < 4; ++i) {
                const int dst = sdst + 16 * i * 64;
                *(uint4*)&KH[cur ^ 1][dst] = kreg[i];
                *(uint4*)&KL[cur ^ 1][dst] = lreg[i];
                *(uint4*)&VT[cur ^ 1][dst] = vreg[i];
            }
        }
        __syncthreads();
    }

    // ---- epilogue: po -> LDS scratch -> coalesced copy ----
    char* item = PO + (size_t)id * 4352;
    ushort* po = (ushort*)item;
    float*  ml = (float*)(item + 4096);
    ushort* OT = KH[0];
#pragma unroll
    for (int db = 0; db < 4; ++db)
#pragma unroll
        for (int r = 0; r < 4; ++r) {
            const int qq = 16 * w + 4 * g + r;
            OT[qq * 64 + 16 * db + c] = f2bf(o[db][r]);
        }
    if (g == 0) {
        ml[16 * w + c]      = m;
        ml[32 + 16 * w + c] = lsum;
    }
    __syncthreads();
#pragma unroll
    for (int i = 0; i < 2; ++i) {
        const int u2 = tid + 128 * i;
        *(uint4*)&po[u2 * 8] = *(const uint4*)&OT[u2 * 8];
    }
}

// ---------------------------------------------------------------------------
__global__ __launch_bounds__(256)
void attn_combine(const char* __restrict__ PO, float* __restrict__ out)
{
    const int qbg = blockIdx.x;            // 0..255
    const int b   = qbg >> 6, qb = qbg & 63;
    const int g   = qb >> 3, np = g + 1;
    const int base = b * 288 + 4 * g * (g + 1) + (qb - 8 * g) * (g + 1);
    const int tid = threadIdx.x;
    const int row = tid >> 3, c8 = tid & 7;

    float M = -1e30f;
    for (int p = 0; p < np; ++p) {
        const float* ml = (const float*)(PO + (size_t)(base + p) * 4352 + 4096);
        M = fmaxf(M, ml[row]);
    }
    float L = 0.f;
    float acc[8];
#pragma unroll
    for (int j = 0; j < 8; ++j) acc[j] = 0.f;
    for (int p = 0; p < np; ++p) {
        const char* item = PO + (size_t)(base + p) * 4352;
        const float* ml  = (const float*)(item + 4096);
        const float wgt  = __expf(ml[row] - M);
        L += wgt * ml[32 + row];
        const ushort* po = (const ushort*)item;
        ushort4 a0 = *(const ushort4*)&po[row * 64 + c8 * 8];
        ushort4 a1 = *(const ushort4*)&po[row * 64 + c8 * 8 + 4];
        acc[0] += wgt * bf2f(a0.x); acc[1] += wgt * bf2f(a0.y);
        acc[2] += wgt * bf2f(a0.z); acc[3] += wgt * bf2f(a0.w);
        acc[4] += wgt * bf2f(a1.x); acc[5] += wgt * bf2f(a1.y);
        acc[6] += wgt * bf2f(a1.z); acc[7] += wgt * bf2f(a1.w);
    }
    const float inv = 1.f / L;
    float* dst = &out[((size_t)(b * SEQ + qb * 32 + row)) * HEAD + c8 * 8];
    *(float4*)dst       = make_float4(acc[0] * inv, acc[1] * inv, acc[2] * inv, acc[3] * inv);
    *(float4*)(dst + 4) = make_float4(acc[4] * inv, acc[5] * inv, acc[6] * inv, acc[7] * inv);
}

// ---------------------------------------------------------------------------

extern "C" void kernel_launch(void* const* d_in, const int* in_sizes, int n_in,
                              void* d_out, int out_size, void* d_ws, size_t ws_size,
                              hipStream_t stream)
{
    // setup_inputs order: x, Wk, Wq, Wv
    const float* x  = (const float*)d_in[0];
    const float* Wk = (const float*)d_in[1];
    const float* Wq = (const float*)d_in[2];
    const float* Wv = (const float*)d_in[3];

    char* ws = (char*)d_ws;
    // layout: Wt 655,360 | Qh/Ql/Kh/Kl/Vr/Vt 6 x 1,048,576 | PO 5,013,504
    ushort* Wt = (ushort*)ws;
    ushort* Qh = (ushort*)(ws +  655360);
    ushort* Ql = (ushort*)(ws + 1703936);
    ushort* Kh = (ushort*)(ws + 2752512);
    ushort* Kl = (ushort*)(ws + 3801088);
    ushort* Vr = (ushort*)(ws + 4849664);
    ushort* Vt = (ushort*)(ws + 5898240);
    char*   PO = ws + 6946816;             // total 11,960,320 B

    prep_w      <<<dim3(160),  256, 0, stream>>>(Wq, Wk, Wv, Wt);
    qkv_fused   <<<dim3(512),  256, 0, stream>>>(x, Wt, Qh, Ql, Kh, Kl, Vr);
    v_transpose <<<dim3(32),   256, 0, stream>>>(Vr, Vt);
    attn_mfma   <<<dim3(1152), 128, 0, stream>>>(Qh, Ql, Kh, Kl, Vt, PO);
    attn_combine<<<dim3(256),  256, 0, stream>>>(PO, (float*)d_out);
}